// Round 1
// baseline (2787.146 us; speedup 1.0000x reference)
//
#include <hip/hip_runtime.h>

#define D 128
#define KC 32

// ---------------- GEMM: hW[N][128] = h[N][128] @ W[128][128] (f32) -------------
// Block: 256 threads, tile 128 rows x 128 cols, K chunked by 32.
// Each thread computes an 8x8 register tile.
__global__ __launch_bounds__(256) void gemm_k(const float* __restrict__ h,
                                              const float* __restrict__ W,
                                              float* __restrict__ hW, int N) {
    __shared__ float Wl[KC][D];   // 16 KB: W[kc..kc+31][0..127]
    __shared__ float hT[KC][D];   // 16 KB: transposed h tile, hT[k][row]
    const int tid  = threadIdx.x;
    const int row0 = blockIdx.x * 128;
    const int ty = tid >> 4;      // 0..15 row group (8 rows each)
    const int tx = tid & 15;      // 0..15 col group (8 cols each)

    float acc[8][8];
#pragma unroll
    for (int i = 0; i < 8; ++i)
#pragma unroll
        for (int j = 0; j < 8; ++j) acc[i][j] = 0.f;

    for (int kc = 0; kc < D; kc += KC) {
        // stage W chunk: 32x128 floats = 1024 float4, 4 per thread
        {
            const float4* Wg  = (const float4*)(W + (size_t)kc * D);
            float4*       Wl4 = (float4*)&Wl[0][0];
#pragma unroll
            for (int i = 0; i < 4; ++i) Wl4[tid + i * 256] = Wg[tid + i * 256];
        }
        // stage h chunk transposed: rows row0..row0+127, cols kc..kc+31
        {
            const int cc = (tid & 7) * 4;          // k offset within chunk
#pragma unroll
            for (int i = 0; i < 4; ++i) {
                int rr  = (tid >> 3) + i * 32;     // 0..127 row within tile
                int row = row0 + rr;
                row = row < N ? row : N - 1;       // clamp (dup work, stores guarded)
                float4 v = *(const float4*)(h + (size_t)row * D + kc + cc);
                hT[cc + 0][rr] = v.x;
                hT[cc + 1][rr] = v.y;
                hT[cc + 2][rr] = v.z;
                hT[cc + 3][rr] = v.w;
            }
        }
        __syncthreads();
#pragma unroll
        for (int k = 0; k < KC; ++k) {
            float4 ha = *(const float4*)(&hT[k][ty * 8]);
            float4 hb = *(const float4*)(&hT[k][ty * 8 + 4]);
            float4 wa = *(const float4*)(&Wl[k][tx * 8]);
            float4 wb = *(const float4*)(&Wl[k][tx * 8 + 4]);
            float hv[8] = {ha.x, ha.y, ha.z, ha.w, hb.x, hb.y, hb.z, hb.w};
            float wv[8] = {wa.x, wa.y, wa.z, wa.w, wb.x, wb.y, wb.z, wb.w};
#pragma unroll
            for (int i = 0; i < 8; ++i)
#pragma unroll
                for (int j = 0; j < 8; ++j) acc[i][j] += hv[i] * wv[j];
        }
        __syncthreads();
    }
    // write out
#pragma unroll
    for (int i = 0; i < 8; ++i) {
        int row = row0 + ty * 8 + i;
        if (row < N) {
            float4* o4 = (float4*)(hW + (size_t)row * D + tx * 8);
            o4[0] = make_float4(acc[i][0], acc[i][1], acc[i][2], acc[i][3]);
            o4[1] = make_float4(acc[i][4], acc[i][5], acc[i][6], acc[i][7]);
        }
    }
}

// ---------------- count: cnt[dst[e]] += 1 ------------------------------------
__global__ void count_k(const int* __restrict__ dst, float* __restrict__ cnt,
                        int E) {
    int i = blockIdx.x * blockDim.x + threadIdx.x;
    if (i < E) atomicAdd(&cnt[dst[i]], 1.0f);
}

// ---------------- inv: inv[i] = 1/(3*max(cnt,1)) -----------------------------
__global__ void inv_k(const float* __restrict__ cnt, float* __restrict__ inv,
                      int n) {
    int i = blockIdx.x * blockDim.x + threadIdx.x;
    if (i < n) inv[i] = 1.0f / (3.0f * fmaxf(cnt[i], 1.0f));
}

// ---------------- scatter: out[dst] += hW[src] * inv[dst] (atomic) -----------
// 32 threads per edge, float4 per thread (128 floats per edge).
__global__ __launch_bounds__(256) void scatter_k(const float* __restrict__ hW,
                                                 const int* __restrict__ src,
                                                 const int* __restrict__ dst,
                                                 const float* __restrict__ inv,
                                                 float* __restrict__ out, int E) {
    int e = blockIdx.x * 8 + (threadIdx.x >> 5);
    if (e >= E) return;
    int lane = threadIdx.x & 31;
    int s = src[e];
    int d = dst[e];
    float scale = inv[d];
    float4 v = ((const float4*)(hW + (size_t)s * D))[lane];
    float* op = out + (size_t)d * D + lane * 4;
    atomicAdd(op + 0, v.x * scale);
    atomicAdd(op + 1, v.y * scale);
    atomicAdd(op + 2, v.z * scale);
    atomicAdd(op + 3, v.w * scale);
}

extern "C" void kernel_launch(void* const* d_in, const int* in_sizes, int n_in,
                              void* d_out, int out_size, void* d_ws, size_t ws_size,
                              hipStream_t stream) {
    const float* h   = (const float*)d_in[0];
    const float* W   = (const float*)d_in[1];
    const int*   src = (const int*)d_in[2];
    const int*   dst = (const int*)d_in[3];
    float*       out = (float*)d_out;

    const int N = in_sizes[0] / D;     // 100000
    const int R = 3;
    const int E = in_sizes[2] / R;     // 500000

    // ws layout: hW [N*128] | cnt [3*N] | inv [3*N]
    float* hW  = (float*)d_ws;
    float* cnt = hW + (size_t)N * D;
    float* inv = cnt + (size_t)R * N;

    hipMemsetAsync(cnt, 0, (size_t)R * N * sizeof(float), stream);
    hipMemcpyAsync(out, h, (size_t)N * D * sizeof(float),
                   hipMemcpyDeviceToDevice, stream);

    for (int r = 0; r < R; ++r)
        count_k<<<(E + 255) / 256, 256, 0, stream>>>(dst + (size_t)r * E,
                                                     cnt + (size_t)r * N, E);
    inv_k<<<(R * N + 255) / 256, 256, 0, stream>>>(cnt, inv, R * N);

    for (int r = 0; r < R; ++r) {
        gemm_k<<<(N + 127) / 128, 256, 0, stream>>>(
            h, W + (size_t)r * D * D, hW, N);
        scatter_k<<<(E + 7) / 8, 256, 0, stream>>>(
            hW, src + (size_t)r * E, dst + (size_t)r * E,
            inv + (size_t)r * N, out, E);
    }
}

// Round 2
// 465.658 us; speedup vs baseline: 5.9854x; 5.9854x over previous
//
#include <hip/hip_runtime.h>

#define D 128
#define KC 32

// ---------------- GEMM: out[N][128] = addend[N][128] + A[N][128] @ W[128][128]
// Block: 256 threads, tile 128 rows x 128 cols, K chunked by 32.
// Each thread computes an 8x8 register tile.
__global__ __launch_bounds__(256) void gemm_acc_k(const float* __restrict__ A,
                                                  const float* __restrict__ W,
                                                  const float* __restrict__ addend,
                                                  float* __restrict__ out, int N) {
    __shared__ float Wl[KC][D];   // 16 KB
    __shared__ float hT[KC][D];   // 16 KB (transposed A tile)
    const int tid  = threadIdx.x;
    const int row0 = blockIdx.x * 128;
    const int ty = tid >> 4;
    const int tx = tid & 15;

    float acc[8][8];
#pragma unroll
    for (int i = 0; i < 8; ++i)
#pragma unroll
        for (int j = 0; j < 8; ++j) acc[i][j] = 0.f;

    for (int kc = 0; kc < D; kc += KC) {
        {
            const float4* Wg  = (const float4*)(W + (size_t)kc * D);
            float4*       Wl4 = (float4*)&Wl[0][0];
#pragma unroll
            for (int i = 0; i < 4; ++i) Wl4[tid + i * 256] = Wg[tid + i * 256];
        }
        {
            const int cc = (tid & 7) * 4;
#pragma unroll
            for (int i = 0; i < 4; ++i) {
                int rr  = (tid >> 3) + i * 32;
                int row = row0 + rr;
                row = row < N ? row : N - 1;
                float4 v = *(const float4*)(A + (size_t)row * D + kc + cc);
                hT[cc + 0][rr] = v.x;
                hT[cc + 1][rr] = v.y;
                hT[cc + 2][rr] = v.z;
                hT[cc + 3][rr] = v.w;
            }
        }
        __syncthreads();
#pragma unroll
        for (int k = 0; k < KC; ++k) {
            float4 ha = *(const float4*)(&hT[k][ty * 8]);
            float4 hb = *(const float4*)(&hT[k][ty * 8 + 4]);
            float4 wa = *(const float4*)(&Wl[k][tx * 8]);
            float4 wb = *(const float4*)(&Wl[k][tx * 8 + 4]);
            float hv[8] = {ha.x, ha.y, ha.z, ha.w, hb.x, hb.y, hb.z, hb.w};
            float wv[8] = {wa.x, wa.y, wa.z, wa.w, wb.x, wb.y, wb.z, wb.w};
#pragma unroll
            for (int i = 0; i < 8; ++i)
#pragma unroll
                for (int j = 0; j < 8; ++j) acc[i][j] += hv[i] * wv[j];
        }
        __syncthreads();
    }
#pragma unroll
    for (int i = 0; i < 8; ++i) {
        int row = row0 + ty * 8 + i;
        if (row < N) {
            const float4* a4 = (const float4*)(addend + (size_t)row * D + tx * 8);
            float4* o4 = (float4*)(out + (size_t)row * D + tx * 8);
            float4 b0 = a4[0], b1 = a4[1];
            o4[0] = make_float4(b0.x + acc[i][0], b0.y + acc[i][1],
                                b0.z + acc[i][2], b0.w + acc[i][3]);
            o4[1] = make_float4(b1.x + acc[i][4], b1.y + acc[i][5],
                                b1.z + acc[i][6], b1.w + acc[i][7]);
        }
    }
}

// ---------------- count: cnt[base + dst[e]]++ --------------------------------
__global__ void count_k(const int* __restrict__ dst, int* __restrict__ cnt,
                        int E, int base) {
    int i = blockIdx.x * blockDim.x + threadIdx.x;
    if (i < E) atomicAdd(&cnt[base + dst[i]], 1);
}

// ---------------- exclusive scan, 3-kernel two-level -------------------------
__global__ void scan_blk_k(const int* __restrict__ cnt, int* __restrict__ off,
                           int* __restrict__ bsum, int n) {
    __shared__ int s[256];
    int i = blockIdx.x * 256 + threadIdx.x;
    int v = (i < n) ? cnt[i] : 0;
    s[threadIdx.x] = v;
    __syncthreads();
    for (int d = 1; d < 256; d <<= 1) {
        int t = (threadIdx.x >= d) ? s[threadIdx.x - d] : 0;
        __syncthreads();
        s[threadIdx.x] += t;
        __syncthreads();
    }
    if (i < n) off[i] = s[threadIdx.x] - v;   // exclusive
    if (threadIdx.x == 255) bsum[blockIdx.x] = s[255];
}

__global__ void scan_top_k(int* __restrict__ bsum, int nb) {
    __shared__ int s[256];
    __shared__ int carry;
    if (threadIdx.x == 0) carry = 0;
    __syncthreads();
    for (int base = 0; base < nb; base += 256) {
        int i = base + threadIdx.x;
        int v = (i < nb) ? bsum[i] : 0;
        s[threadIdx.x] = v;
        __syncthreads();
        for (int d = 1; d < 256; d <<= 1) {
            int t = (threadIdx.x >= d) ? s[threadIdx.x - d] : 0;
            __syncthreads();
            s[threadIdx.x] += t;
            __syncthreads();
        }
        if (i < nb) bsum[i] = s[threadIdx.x] - v + carry;  // exclusive + carry
        __syncthreads();
        if (threadIdx.x == 255) carry += s[255];
        __syncthreads();
    }
}

__global__ void scan_add_k(int* __restrict__ off, int* __restrict__ cursor,
                           const int* __restrict__ bsum, int n, int total) {
    int i = blockIdx.x * 256 + threadIdx.x;
    if (i < n) {
        int v = off[i] + bsum[blockIdx.x];
        off[i] = v;
        cursor[i] = v;
    }
    if (i == 0) off[n] = total;
}

// ---------------- build perm: sorted-by-(r,dst) src ids ----------------------
__global__ void build_perm_k(const int* __restrict__ src,
                             const int* __restrict__ dst,
                             int* __restrict__ cursor, int* __restrict__ perm,
                             int E, int base) {
    int i = blockIdx.x * blockDim.x + threadIdx.x;
    if (i < E) {
        int pos = atomicAdd(&cursor[base + dst[i]], 1);
        perm[pos] = src[i];
    }
}

// ---------------- agg: agg[n] = (1/(3*max(cnt,1))) * sum_{e in seg} h[perm[e]]
// 32 lanes per node, float4 per lane.
__global__ __launch_bounds__(256) void agg_k(const float* __restrict__ h,
                                             const int* __restrict__ perm,
                                             const int* __restrict__ off,
                                             float* __restrict__ agg,
                                             int N, int base) {
    int n = blockIdx.x * 8 + (threadIdx.x >> 5);
    if (n >= N) return;
    int lane = threadIdx.x & 31;
    int beg = off[base + n], end = off[base + n + 1];
    float4 acc = make_float4(0.f, 0.f, 0.f, 0.f);
    for (int e = beg; e < end; ++e) {
        int s = perm[e];
        float4 v = ((const float4*)(h + (size_t)s * D))[lane];
        acc.x += v.x; acc.y += v.y; acc.z += v.z; acc.w += v.w;
    }
    float scale = 1.0f / (3.0f * fmaxf((float)(end - beg), 1.0f));
    ((float4*)(agg + (size_t)n * D))[lane] =
        make_float4(acc.x * scale, acc.y * scale, acc.z * scale, acc.w * scale);
}

extern "C" void kernel_launch(void* const* d_in, const int* in_sizes, int n_in,
                              void* d_out, int out_size, void* d_ws, size_t ws_size,
                              hipStream_t stream) {
    const float* h   = (const float*)d_in[0];
    const float* W   = (const float*)d_in[1];
    const int*   src = (const int*)d_in[2];
    const int*   dst = (const int*)d_in[3];
    float*       out = (float*)d_out;

    const int N = in_sizes[0] / D;     // 100000
    const int R = 3;
    const int E = in_sizes[2] / R;     // 500000
    const int RN = R * N;
    const int nBlocksScan = (RN + 255) / 256;

    // ws layout: agg [N*128 f32] | cnt [RN] | off [RN+1] | cursor [RN] |
    //            bsum [nBlocksScan] | perm [R*E]
    float* agg    = (float*)d_ws;
    int*   cnt    = (int*)(agg + (size_t)N * D);
    int*   off    = cnt + RN;
    int*   cursor = off + RN + 1;
    int*   bsum   = cursor + RN;
    int*   perm   = bsum + nBlocksScan;

    hipMemsetAsync(cnt, 0, (size_t)RN * sizeof(int), stream);

    for (int r = 0; r < R; ++r)
        count_k<<<(E + 255) / 256, 256, 0, stream>>>(dst + (size_t)r * E, cnt, E, r * N);

    scan_blk_k<<<nBlocksScan, 256, 0, stream>>>(cnt, off, bsum, RN);
    scan_top_k<<<1, 256, 0, stream>>>(bsum, nBlocksScan);
    scan_add_k<<<nBlocksScan, 256, 0, stream>>>(off, cursor, bsum, RN, R * E);

    for (int r = 0; r < R; ++r)
        build_perm_k<<<(E + 255) / 256, 256, 0, stream>>>(
            src + (size_t)r * E, dst + (size_t)r * E, cursor, perm, E, r * N);

    for (int r = 0; r < R; ++r) {
        agg_k<<<(N + 7) / 8, 256, 0, stream>>>(h, perm, off, agg, N, r * N);
        gemm_acc_k<<<(N + 127) / 128, 256, 0, stream>>>(
            agg, W + (size_t)r * D * D, (r == 0) ? h : out, out, N);
    }
}

// Round 3
// 343.217 us; speedup vs baseline: 8.1206x; 1.3567x over previous
//
#include <hip/hip_runtime.h>

#define D 128

typedef short short8 __attribute__((ext_vector_type(8)));
typedef float f32x4 __attribute__((ext_vector_type(4)));

// round-to-nearest-even f32 -> bf16 bits
__device__ __forceinline__ unsigned int f2bf(float x) {
    unsigned int u = __float_as_uint(x);
    return (u + 0x7fffu + ((u >> 16) & 1u)) >> 16;
}

// ---------------- h f32 -> bf16 (row-major [N][128]) -------------------------
__global__ __launch_bounds__(256) void conv_h_k(const float* __restrict__ h,
                                                unsigned short* __restrict__ hb,
                                                int n8) {
    int i = blockIdx.x * 256 + threadIdx.x;
    if (i >= n8) return;
    const float4* hp = (const float4*)h;
    float4 v0 = hp[2 * i + 0], v1 = hp[2 * i + 1];
    uint4 o;
    o.x = f2bf(v0.x) | (f2bf(v0.y) << 16);
    o.y = f2bf(v0.z) | (f2bf(v0.w) << 16);
    o.z = f2bf(v1.x) | (f2bf(v1.y) << 16);
    o.w = f2bf(v1.z) | (f2bf(v1.w) << 16);
    ((uint4*)hb)[i] = o;
}

// ---------------- W pack: B-fragment order [12][8][64][8] bf16 ---------------
// B[k][col]: lane l supplies k = kg*32 + (l>>4)*8 + j, col = cg*16 + (l&15).
// Source W is [R][d_in][d_out]; global k = r*128 + k_local.
__global__ void pack_w_k(const float* __restrict__ W,
                         unsigned short* __restrict__ Wb) {
    int t = blockIdx.x * 256 + threadIdx.x;
    if (t >= 12 * 8 * 64) return;
    int lane = t & 63, cg = (t >> 6) & 7, kg = t >> 9;
    int col = cg * 16 + (lane & 15);
    int r = kg >> 2;
    int klocal = (kg & 3) * 32 + (lane >> 4) * 8;
    const float* Ws = W + ((size_t)r * D + klocal) * D + col;
    uint4 o;
    o.x = f2bf(Ws[0 * D]) | (f2bf(Ws[1 * D]) << 16);
    o.y = f2bf(Ws[2 * D]) | (f2bf(Ws[3 * D]) << 16);
    o.z = f2bf(Ws[4 * D]) | (f2bf(Ws[5 * D]) << 16);
    o.w = f2bf(Ws[6 * D]) | (f2bf(Ws[7 * D]) << 16);
    ((uint4*)Wb)[t] = o;
}

// ---------------- count: cnt[r*N + dst]++ over all R*E edges -----------------
__global__ void count_k(const int* __restrict__ dst, int* __restrict__ cnt,
                        int E, int N, int nbE) {
    int r = blockIdx.x / nbE;
    int i = (blockIdx.x - r * nbE) * 256 + threadIdx.x;
    if (i < E) atomicAdd(&cnt[r * N + dst[(size_t)r * E + i]], 1);
}

// ---------------- exclusive scan, two-level ----------------------------------
__global__ void scan_blk_k(const int* __restrict__ cnt, int* __restrict__ off,
                           int* __restrict__ bsum, int n) {
    __shared__ int s[256];
    int i = blockIdx.x * 256 + threadIdx.x;
    int v = (i < n) ? cnt[i] : 0;
    s[threadIdx.x] = v;
    __syncthreads();
    for (int d = 1; d < 256; d <<= 1) {
        int t = (threadIdx.x >= d) ? s[threadIdx.x - d] : 0;
        __syncthreads();
        s[threadIdx.x] += t;
        __syncthreads();
    }
    if (i < n) off[i] = s[threadIdx.x] - v;
    if (threadIdx.x == 255) bsum[blockIdx.x] = s[255];
}

__global__ void scan_top_k(int* __restrict__ bsum, int nb) {
    __shared__ int s[256];
    __shared__ int carry;
    if (threadIdx.x == 0) carry = 0;
    __syncthreads();
    for (int base = 0; base < nb; base += 256) {
        int i = base + threadIdx.x;
        int v = (i < nb) ? bsum[i] : 0;
        s[threadIdx.x] = v;
        __syncthreads();
        for (int d = 1; d < 256; d <<= 1) {
            int t = (threadIdx.x >= d) ? s[threadIdx.x - d] : 0;
            __syncthreads();
            s[threadIdx.x] += t;
            __syncthreads();
        }
        if (i < nb) bsum[i] = s[threadIdx.x] - v + carry;
        __syncthreads();
        if (threadIdx.x == 255) carry += s[255];
        __syncthreads();
    }
}

__global__ void scan_add_k(int* __restrict__ off, int* __restrict__ cursor,
                           const int* __restrict__ bsum, int n, int total) {
    int i = blockIdx.x * 256 + threadIdx.x;
    if (i < n) {
        int v = off[i] + bsum[blockIdx.x];
        off[i] = v;
        cursor[i] = v;
    }
    if (i == 0) off[n] = total;
}

// ---------------- build perm: src ids sorted by (r,dst) ----------------------
__global__ void build_perm_k(const int* __restrict__ src,
                             const int* __restrict__ dst,
                             int* __restrict__ cursor, int* __restrict__ perm,
                             int E, int N, int nbE) {
    int r = blockIdx.x / nbE;
    int i = (blockIdx.x - r * nbE) * 256 + threadIdx.x;
    if (i < E) {
        int pos = atomicAdd(&cursor[r * N + dst[(size_t)r * E + i]], 1);
        perm[pos] = src[(size_t)r * E + i];
    }
}

// ---------------- agg: segment-mean of h rows, written A-fragment-packed -----
// Block = 256 threads = one 16-node row group. Thread t owns packed slot
// (kgl = t>>6, lane = t&63): node = grp*16 + (lane&15),
// features c = kgl*32 + (lane>>4)*8 .. +7 (8 bf16 = one uint4 slot).
// Store: A[((grp*KS + kgb + kgl)*64 + lane)] (uint4) -- fully coalesced.
__global__ __launch_bounds__(256) void agg_k(
    const unsigned short* __restrict__ hb, const int* __restrict__ perm,
    const int* __restrict__ off, unsigned short* __restrict__ A,
    int N, int KS, int kgb) {
    int grp = blockIdx.x;
    int lane = threadIdx.x & 63;
    int kgl = threadIdx.x >> 6;
    int n = grp * 16 + (lane & 15);
    if (n >= N) n = N - 1;
    int c = kgl * 32 + (lane >> 4) * 8;
    int beg = off[n], end = off[n + 1];
    float a0 = 0, a1 = 0, a2 = 0, a3 = 0, a4 = 0, a5 = 0, a6 = 0, a7 = 0;
    for (int e = beg; e < end; ++e) {
        int s = perm[e];
        uint4 u = *(const uint4*)(hb + ((size_t)s << 7) + c);
        a0 += __uint_as_float(u.x << 16);
        a1 += __uint_as_float(u.x & 0xffff0000u);
        a2 += __uint_as_float(u.y << 16);
        a3 += __uint_as_float(u.y & 0xffff0000u);
        a4 += __uint_as_float(u.z << 16);
        a5 += __uint_as_float(u.z & 0xffff0000u);
        a6 += __uint_as_float(u.w << 16);
        a7 += __uint_as_float(u.w & 0xffff0000u);
    }
    float sc = 1.0f / (3.0f * fmaxf((float)(end - beg), 1.0f));
    uint4 o;
    o.x = f2bf(a0 * sc) | (f2bf(a1 * sc) << 16);
    o.y = f2bf(a2 * sc) | (f2bf(a3 * sc) << 16);
    o.z = f2bf(a4 * sc) | (f2bf(a5 * sc) << 16);
    o.w = f2bf(a6 * sc) | (f2bf(a7 * sc) << 16);
    ((uint4*)A)[((size_t)grp * KS + kgb + kgl) * 64 + lane] = o;
}

// ---------------- MFMA GEMM, no LDS, fragments straight from global ----------
// out[row][col] = addend[row][col] + sum_k A[row][k]*B[k][col]
// 4 waves: 2x2 over a 128x128 tile; each wave 64x64 = 4x4 fragments of 16x16.
// A packed [NG][KG][64][8]; B packed [12][8][64][8] (kgB offsets into B).
template <int KG>
__global__ __launch_bounds__(256) void gemm_k(
    const unsigned short* __restrict__ A, const unsigned short* __restrict__ B,
    const float* __restrict__ addend, float* __restrict__ out, int N, int NG,
    int kgB) {
    int lane = threadIdx.x & 63;
    int w = threadIdx.x >> 6;
    int wr = w >> 1, wc = w & 1;
    int rg0 = blockIdx.x * 8 + wr * 4;
    const short8* Ap = (const short8*)A;
    const short8* Bp = (const short8*)B;
    f32x4 acc[4][4];
#pragma unroll
    for (int m = 0; m < 4; ++m)
#pragma unroll
        for (int n = 0; n < 4; ++n) acc[m][n] = (f32x4){0.f, 0.f, 0.f, 0.f};
#pragma unroll 2
    for (int kg = 0; kg < KG; ++kg) {
        short8 a[4], b[4];
#pragma unroll
        for (int m = 0; m < 4; ++m) {
            int rg = rg0 + m;
            rg = rg < NG ? rg : NG - 1;
            a[m] = Ap[((size_t)rg * KG + kg) * 64 + lane];
        }
#pragma unroll
        for (int n = 0; n < 4; ++n)
            b[n] = Bp[(((size_t)(kgB + kg)) * 8 + wc * 4 + n) * 64 + lane];
#pragma unroll
        for (int m = 0; m < 4; ++m)
#pragma unroll
            for (int n = 0; n < 4; ++n)
                acc[m][n] = __builtin_amdgcn_mfma_f32_16x16x32_bf16(
                    a[m], b[n], acc[m][n], 0, 0, 0);
    }
    // D layout (m89-verified): col = lane&15, row = (lane>>4)*4 + reg
    int col0 = wc * 64 + (lane & 15);
    int rbase = blockIdx.x * 128 + wr * 64 + ((lane >> 4) << 2);
#pragma unroll
    for (int m = 0; m < 4; ++m)
#pragma unroll
        for (int r = 0; r < 4; ++r) {
            int row = rbase + m * 16 + r;
            if (row < N) {
                const float* ap = addend + ((size_t)row << 7) + col0;
                float* op = out + ((size_t)row << 7) + col0;
#pragma unroll
                for (int n = 0; n < 4; ++n)
                    op[n * 16] = ap[n * 16] + acc[m][n][r];
            }
        }
}

extern "C" void kernel_launch(void* const* d_in, const int* in_sizes, int n_in,
                              void* d_out, int out_size, void* d_ws, size_t ws_size,
                              hipStream_t stream) {
    const float* h = (const float*)d_in[0];
    const float* W = (const float*)d_in[1];
    const int* src = (const int*)d_in[2];
    const int* dst = (const int*)d_in[3];
    float* out = (float*)d_out;

    const int N = in_sizes[0] / D;     // 100000
    const int R = 3;
    const int E = in_sizes[2] / R;     // 500000
    const int RN = R * N;
    const int NG = (N + 15) / 16;      // 6250 row groups
    const int nbScan = (RN + 255) / 256;
    const int nbE = (E + 255) / 256;

    auto al16 = [](size_t x) { return (x + 15) & ~(size_t)15; };
    size_t sz_hb = al16((size_t)N * D * 2);
    size_t sz_Wb = al16((size_t)12 * 8 * 64 * 8 * 2);
    size_t sz_cnt = al16((size_t)RN * 4);
    size_t sz_off = al16(((size_t)RN + 1) * 4);
    size_t sz_cur = al16((size_t)RN * 4);
    size_t sz_bs = al16((size_t)nbScan * 4);
    size_t sz_perm = al16((size_t)R * E * 4);
    size_t fixed = sz_hb + sz_Wb + sz_cnt + sz_off + sz_cur + sz_bs + sz_perm;
    size_t sz_A12 = (size_t)NG * 12 * 512 * 2;   // K=384 fused A
    bool fused = ws_size >= fixed + al16(sz_A12);
    size_t sz_A = al16((size_t)NG * (fused ? 12 : 4) * 512 * 2);

    char* p = (char*)d_ws;
    unsigned short* A  = (unsigned short*)p; p += sz_A;
    unsigned short* hb = (unsigned short*)p; p += sz_hb;
    unsigned short* Wb = (unsigned short*)p; p += sz_Wb;
    int* cnt    = (int*)p; p += sz_cnt;
    int* off    = (int*)p; p += sz_off;
    int* cursor = (int*)p; p += sz_cur;
    int* bsum   = (int*)p; p += sz_bs;
    int* perm   = (int*)p; p += sz_perm;

    hipMemsetAsync(cnt, 0, (size_t)RN * 4, stream);
    count_k<<<R * nbE, 256, 0, stream>>>(dst, cnt, E, N, nbE);
    scan_blk_k<<<nbScan, 256, 0, stream>>>(cnt, off, bsum, RN);
    scan_top_k<<<1, 256, 0, stream>>>(bsum, nbScan);
    scan_add_k<<<nbScan, 256, 0, stream>>>(off, cursor, bsum, RN, R * E);
    build_perm_k<<<R * nbE, 256, 0, stream>>>(src, dst, cursor, perm, E, N, nbE);
    conv_h_k<<<(N * D / 8 + 255) / 256, 256, 0, stream>>>(h, hb, N * D / 8);
    pack_w_k<<<(12 * 8 * 64 + 255) / 256, 256, 0, stream>>>(W, Wb);

    int gblk = (NG + 7) / 8;
    if (fused) {
        for (int r = 0; r < R; ++r)
            agg_k<<<NG, 256, 0, stream>>>(hb, perm, off + (size_t)r * N, A,
                                          N, 12, r * 4);
        gemm_k<12><<<gblk, 256, 0, stream>>>(A, Wb, h, out, N, NG, 0);
    } else {
        for (int r = 0; r < R; ++r) {
            agg_k<<<NG, 256, 0, stream>>>(hb, perm, off + (size_t)r * N, A,
                                          N, 4, 0);
            gemm_k<4><<<gblk, 256, 0, stream>>>(A, Wb, (r == 0) ? h : out, out,
                                                N, NG, r * 4);
        }
    }
}

// Round 4
// 218.315 us; speedup vs baseline: 12.7666x; 1.5721x over previous
//
#include <hip/hip_runtime.h>

#define D 128

typedef short short8 __attribute__((ext_vector_type(8)));
typedef float f32x4 __attribute__((ext_vector_type(4)));

// round-to-nearest-even f32 -> bf16 bits
__device__ __forceinline__ unsigned int f2bf(float x) {
    unsigned int u = __float_as_uint(x);
    return (u + 0x7fffu + ((u >> 16) & 1u)) >> 16;
}

// ---------------- h f32 -> bf16 (row-major [N][128]) -------------------------
__global__ __launch_bounds__(256) void conv_h_k(const float* __restrict__ h,
                                                unsigned short* __restrict__ hb,
                                                int n8) {
    int i = blockIdx.x * 256 + threadIdx.x;
    if (i >= n8) return;
    const float4* hp = (const float4*)h;
    float4 v0 = hp[2 * i + 0], v1 = hp[2 * i + 1];
    uint4 o;
    o.x = f2bf(v0.x) | (f2bf(v0.y) << 16);
    o.y = f2bf(v0.z) | (f2bf(v0.w) << 16);
    o.z = f2bf(v1.x) | (f2bf(v1.y) << 16);
    o.w = f2bf(v1.z) | (f2bf(v1.w) << 16);
    ((uint4*)hb)[i] = o;
}

// ---------------- W pack: B-fragment order [12][8][64][8] bf16 ---------------
// B[k][col]: lane l supplies k = kg*32 + (l>>4)*8 + j, col = cg*16 + (l&15).
// Source W is [R][d_in][d_out]; global k = r*128 + k_local.
__global__ void pack_w_k(const float* __restrict__ W,
                         unsigned short* __restrict__ Wb) {
    int t = blockIdx.x * 256 + threadIdx.x;
    if (t >= 12 * 8 * 64) return;
    int lane = t & 63, cg = (t >> 6) & 7, kg = t >> 9;
    int col = cg * 16 + (lane & 15);
    int r = kg >> 2;
    int klocal = (kg & 3) * 32 + (lane >> 4) * 8;
    const float* Ws = W + ((size_t)r * D + klocal) * D + col;
    uint4 o;
    o.x = f2bf(Ws[0 * D]) | (f2bf(Ws[1 * D]) << 16);
    o.y = f2bf(Ws[2 * D]) | (f2bf(Ws[3 * D]) << 16);
    o.z = f2bf(Ws[4 * D]) | (f2bf(Ws[5 * D]) << 16);
    o.w = f2bf(Ws[6 * D]) | (f2bf(Ws[7 * D]) << 16);
    ((uint4*)Wb)[t] = o;
}

// ---------------- chain build: one pass, coalesced 8B writes -----------------
// head[r*N + d] = newest edge slot; chain[gi] = (src, prev slot or -1).
__global__ void chain_k(const int* __restrict__ src, const int* __restrict__ dst,
                        int* __restrict__ head, int2* __restrict__ chain,
                        int E, int N, int nbE) {
    int r = blockIdx.x / nbE;
    int i = (blockIdx.x - r * nbE) * 256 + threadIdx.x;
    if (i >= E) return;
    size_t gi = (size_t)r * E + i;
    int d = dst[gi];
    int s = src[gi];
    int old = atomicExch(&head[r * N + d], (int)gi);
    chain[gi] = make_int2(s, old);
}

// ---------------- agg: segment-mean of h rows via chains, A-fragment-packed --
// Block = 256 threads = one 16-node row group of one relation.
// Thread t: node = grp*16 + (lane&15), features c = kgl*32 + (lane>>4)*8 .. +7.
// Store: A[((grp*KS + kgbPerR*r + kgl)*64 + lane)] (uint4) -- coalesced.
__global__ __launch_bounds__(256) void agg_k(
    const unsigned short* __restrict__ hb, const int2* __restrict__ chain,
    const int* __restrict__ head, unsigned short* __restrict__ A,
    int N, int NG, int KS, int kgbPerR, int r0) {
    int r = r0 + blockIdx.x / NG;
    int grp = blockIdx.x % NG;
    int lane = threadIdx.x & 63;
    int kgl = threadIdx.x >> 6;
    int n = grp * 16 + (lane & 15);
    if (n >= N) n = N - 1;
    int c = kgl * 32 + (lane >> 4) * 8;
    float a0 = 0, a1 = 0, a2 = 0, a3 = 0, a4 = 0, a5 = 0, a6 = 0, a7 = 0;
    int e = head[r * N + n];
    int cntE = 0;
    while (e >= 0) {
        int2 ce = chain[e];
        ++cntE;
        uint4 u = *(const uint4*)(hb + ((size_t)ce.x << 7) + c);
        a0 += __uint_as_float(u.x << 16);
        a1 += __uint_as_float(u.x & 0xffff0000u);
        a2 += __uint_as_float(u.y << 16);
        a3 += __uint_as_float(u.y & 0xffff0000u);
        a4 += __uint_as_float(u.z << 16);
        a5 += __uint_as_float(u.z & 0xffff0000u);
        a6 += __uint_as_float(u.w << 16);
        a7 += __uint_as_float(u.w & 0xffff0000u);
        e = ce.y;
    }
    float sc = 1.0f / (3.0f * fmaxf((float)cntE, 1.0f));
    uint4 o;
    o.x = f2bf(a0 * sc) | (f2bf(a1 * sc) << 16);
    o.y = f2bf(a2 * sc) | (f2bf(a3 * sc) << 16);
    o.z = f2bf(a4 * sc) | (f2bf(a5 * sc) << 16);
    o.w = f2bf(a6 * sc) | (f2bf(a7 * sc) << 16);
    ((uint4*)A)[((size_t)grp * KS + kgbPerR * r + kgl) * 64 + lane] = o;
}

// ---------------- MFMA GEMM, no LDS, fragments straight from global ----------
// out[row][col] = addend[row][col] + sum_k A[row][k]*B[k][col]
// 4 waves: 2x2 over a 128x128 tile; each wave 64x64 = 4x4 fragments of 16x16.
// A packed [NG][KG][64][8]; B packed [12][8][64][8] (kgB offsets into B).
template <int KG>
__global__ __launch_bounds__(256) void gemm_k(
    const unsigned short* __restrict__ A, const unsigned short* __restrict__ B,
    const float* __restrict__ addend, float* __restrict__ out, int N, int NG,
    int kgB) {
    int lane = threadIdx.x & 63;
    int w = threadIdx.x >> 6;
    int wr = w >> 1, wc = w & 1;
    int rg0 = blockIdx.x * 8 + wr * 4;
    const short8* Ap = (const short8*)A;
    const short8* Bp = (const short8*)B;
    f32x4 acc[4][4];
#pragma unroll
    for (int m = 0; m < 4; ++m)
#pragma unroll
        for (int n = 0; n < 4; ++n) acc[m][n] = (f32x4){0.f, 0.f, 0.f, 0.f};
#pragma unroll 2
    for (int kg = 0; kg < KG; ++kg) {
        short8 a[4], b[4];
#pragma unroll
        for (int m = 0; m < 4; ++m) {
            int rg = rg0 + m;
            rg = rg < NG ? rg : NG - 1;
            a[m] = Ap[((size_t)rg * KG + kg) * 64 + lane];
        }
#pragma unroll
        for (int n = 0; n < 4; ++n)
            b[n] = Bp[(((size_t)(kgB + kg)) * 8 + wc * 4 + n) * 64 + lane];
#pragma unroll
        for (int m = 0; m < 4; ++m)
#pragma unroll
            for (int n = 0; n < 4; ++n)
                acc[m][n] = __builtin_amdgcn_mfma_f32_16x16x32_bf16(
                    a[m], b[n], acc[m][n], 0, 0, 0);
    }
    // D layout (m89-verified): col = lane&15, row = (lane>>4)*4 + reg
    int col0 = wc * 64 + (lane & 15);
    int rbase = blockIdx.x * 128 + wr * 64 + ((lane >> 4) << 2);
#pragma unroll
    for (int m = 0; m < 4; ++m)
#pragma unroll
        for (int r = 0; r < 4; ++r) {
            int row = rbase + m * 16 + r;
            if (row < N) {
                const float* ap = addend + ((size_t)row << 7) + col0;
                float* op = out + ((size_t)row << 7) + col0;
#pragma unroll
                for (int n = 0; n < 4; ++n)
                    op[n * 16] = ap[n * 16] + acc[m][n][r];
            }
        }
}

extern "C" void kernel_launch(void* const* d_in, const int* in_sizes, int n_in,
                              void* d_out, int out_size, void* d_ws, size_t ws_size,
                              hipStream_t stream) {
    const float* h = (const float*)d_in[0];
    const float* W = (const float*)d_in[1];
    const int* src = (const int*)d_in[2];
    const int* dst = (const int*)d_in[3];
    float* out = (float*)d_out;

    const int N = in_sizes[0] / D;     // 100000
    const int R = 3;
    const int E = in_sizes[2] / R;     // 500000
    const int RN = R * N;
    const int NG = (N + 15) / 16;      // 6250 row groups
    const int nbE = (E + 255) / 256;

    auto al16 = [](size_t x) { return (x + 15) & ~(size_t)15; };
    size_t sz_hb = al16((size_t)N * D * 2);
    size_t sz_Wb = al16((size_t)12 * 8 * 64 * 8 * 2);
    size_t sz_head = al16((size_t)RN * 4);
    size_t sz_chain = al16((size_t)R * E * 8);
    size_t fixed = sz_hb + sz_Wb + sz_head + sz_chain;
    size_t sz_A12 = (size_t)NG * 12 * 512 * 2;   // K=384 fused A
    bool fused = ws_size >= fixed + al16(sz_A12);
    size_t sz_A = al16((size_t)NG * (fused ? 12 : 4) * 512 * 2);

    char* p = (char*)d_ws;
    unsigned short* A  = (unsigned short*)p; p += sz_A;
    unsigned short* hb = (unsigned short*)p; p += sz_hb;
    unsigned short* Wb = (unsigned short*)p; p += sz_Wb;
    int*  head  = (int*)p;  p += sz_head;
    int2* chain = (int2*)p; p += sz_chain;

    hipMemsetAsync(head, 0xFF, (size_t)RN * 4, stream);   // head = -1
    conv_h_k<<<(N * D / 8 + 255) / 256, 256, 0, stream>>>(h, hb, N * D / 8);
    pack_w_k<<<(12 * 8 * 64 + 255) / 256, 256, 0, stream>>>(W, Wb);
    chain_k<<<R * nbE, 256, 0, stream>>>(src, dst, head, chain, E, N, nbE);

    int gblk = (NG + 7) / 8;
    if (fused) {
        agg_k<<<R * NG, 256, 0, stream>>>(hb, chain, head, A, N, NG, 12, 4, 0);
        gemm_k<12><<<gblk, 256, 0, stream>>>(A, Wb, h, out, N, NG, 0);
    } else {
        for (int r = 0; r < R; ++r) {
            agg_k<<<NG, 256, 0, stream>>>(hb, chain, head, A, N, NG, 4, 0, r);
            gemm_k<4><<<gblk, 256, 0, stream>>>(A, Wb, (r == 0) ? h : out, out,
                                                N, NG, r * 4);
        }
    }
}